// Round 1
// baseline (362.410 us; speedup 1.0000x reference)
//
#include <hip/hip_runtime.h>

#define NTOK 4096
#define DIM 1024
#define NE 8

typedef __bf16 bf16x8 __attribute__((ext_vector_type(8)));
typedef float floatx4 __attribute__((ext_vector_type(4)));

__device__ __forceinline__ unsigned short f2bf(float f) {
  unsigned u = __float_as_uint(f);
  u = u + 0x7fffu + ((u >> 16) & 1u);
  return (unsigned short)(u >> 16);
}
__device__ __forceinline__ float bf2f(unsigned short h) {
  return __uint_as_float(((unsigned)h) << 16);
}

__device__ __forceinline__ void gld_lds16(const unsigned short* g, unsigned short* l) {
  __builtin_amdgcn_global_load_lds(
      (const __attribute__((address_space(1))) void*)g,
      (__attribute__((address_space(3))) void*)l, 16, 0, 0);
}

// ---------------- gating: logits, softmax, top-2, bucket scatter, x->bf16 ----------------
__global__ __launch_bounds__(256) void gate_kernel(
    const float* __restrict__ x, const float* __restrict__ gW,
    const float* __restrict__ gb, unsigned short* __restrict__ x_bf,
    float* __restrict__ gp_out, int* __restrict__ cnt,
    int* __restrict__ bucket, float* __restrict__ pairw)
{
  const int t = blockIdx.x;
  const int tid = threadIdx.x;
  const int lane = tid & 63;
  const int wid = tid >> 6;
  __shared__ float red[4][NE];

  float4 xv = ((const float4*)(x + (size_t)t * DIM))[tid];
  ushort4 xb;
  xb.x = f2bf(xv.x); xb.y = f2bf(xv.y); xb.z = f2bf(xv.z); xb.w = f2bf(xv.w);
  ((ushort4*)(x_bf + (size_t)t * DIM))[tid] = xb;

  float p[NE];
#pragma unroll
  for (int e = 0; e < NE; e++) {
    float4 g = ((const float4*)(gW + e * DIM))[tid];
    p[e] = xv.x * g.x + xv.y * g.y + xv.z * g.z + xv.w * g.w;
  }
#pragma unroll
  for (int e = 0; e < NE; e++) {
    float v = p[e];
    v += __shfl_down(v, 32); v += __shfl_down(v, 16); v += __shfl_down(v, 8);
    v += __shfl_down(v, 4);  v += __shfl_down(v, 2);  v += __shfl_down(v, 1);
    if (lane == 0) red[wid][e] = v;
  }
  __syncthreads();
  if (tid == 0) {
    float l[NE], pr[NE];
    float m = -1e30f;
    for (int e = 0; e < NE; e++) {
      l[e] = red[0][e] + red[1][e] + red[2][e] + red[3][e] + gb[e];
      m = fmaxf(m, l[e]);
    }
    float s = 0.f;
    for (int e = 0; e < NE; e++) { pr[e] = __expf(l[e] - m); s += pr[e]; }
    float inv = 1.f / s;
    for (int e = 0; e < NE; e++) { pr[e] *= inv; gp_out[(size_t)t * NE + e] = pr[e]; }
    // top-2 (ties -> lowest index, matching lax.top_k)
    int i0 = 0;
    for (int e = 1; e < NE; e++) if (pr[e] > pr[i0]) i0 = e;
    int i1 = (i0 == 0) ? 1 : 0;
    for (int e = 0; e < NE; e++) if (e != i0 && pr[e] > pr[i1]) i1 = e;
    // renormalize: softmax over the two probabilities (per reference)
    float d = __expf(pr[i1] - pr[i0]);
    float w0 = 1.f / (1.f + d);
    float w1 = 1.f - w0;
    int s0 = atomicAdd(&cnt[i0], 1);
    bucket[i0 * NTOK + s0] = t * 2;
    int s1 = atomicAdd(&cnt[i1], 1);
    bucket[i1 * NTOK + s1] = t * 2 + 1;
    pairw[t * 2] = w0;
    pairw[t * 2 + 1] = w1;
  }
}

// ---------------- fp32 -> bf16 weight conversion ----------------
__global__ __launch_bounds__(256) void cvt_kernel(
    const float4* __restrict__ src, ushort4* __restrict__ dst)
{
  int i = blockIdx.x * 256 + threadIdx.x;
  float4 v = src[i];
  ushort4 o;
  o.x = f2bf(v.x); o.y = f2bf(v.y); o.z = f2bf(v.z); o.w = f2bf(v.w);
  dst[i] = o;
}

// ---------------- grouped expert GEMM (128x128 tile, BK=64, 16x16x32 bf16 MFMA) ----------
// MODE 0: A = x_bf gathered by token (pid>>1), out = relu(acc + b1) -> h[pid]
// MODE 1: A = h gathered by pid,            out = (acc + b2) * pairw[pid] -> o_pair[pid]
template <int MODE>
__global__ __launch_bounds__(256) void ffn_gemm(
    const unsigned short* __restrict__ A,
    const unsigned short* __restrict__ B,     // [E][DIM][DIM] bf16, row-major (out,in)
    const float* __restrict__ bias,           // [E][DIM]
    const int* __restrict__ cnt, const int* __restrict__ bucket,
    const float* __restrict__ pairw,
    unsigned short* __restrict__ Out)
{
  const int nt = blockIdx.x;
  const int mt = blockIdx.y;
  const int e  = blockIdx.z;
  const int n_e = cnt[e];
  if (mt * 128 >= n_e) return;

  __shared__ unsigned short lda[128 * 64];
  __shared__ unsigned short ldb[128 * 64];
  __shared__ int toks[128];

  const int tid = threadIdx.x;
  const int lane = tid & 63;
  const int wid = tid >> 6;

  if (tid < 128) {
    int r = mt * 128 + tid;
    if (r >= n_e) r = n_e - 1;     // clamp: duplicate row, store-masked later
    toks[tid] = bucket[e * NTOK + r];
  }
  __syncthreads();

  // staging addresses: group g = wid*4+j covers tile rows g*8..g*8+7 (1 KiB per inst)
  const unsigned short* aptr[4];
  const unsigned short* bptr[4];
  unsigned short* lap[4];
  unsigned short* lbp[4];
#pragma unroll
  for (int j = 0; j < 4; j++) {
    int g = wid * 4 + j;
    int row = g * 8 + (lane >> 3);
    int pid = toks[row];
    int arow = (MODE == 0) ? (pid >> 1) : pid;
    aptr[j] = A + (size_t)arow * DIM + ((lane & 7) << 3);
    lap[j] = lda + g * 512;
    int brow = nt * 128 + row;
    bptr[j] = B + (size_t)e * DIM * DIM + (size_t)brow * DIM + ((lane & 7) << 3);
    lbp[j] = ldb + g * 512;
  }

  floatx4 acc[4][4] = {};
  const int wm = (wid & 1) * 64;
  const int wn = (wid >> 1) * 64;

  for (int k0 = 0; k0 < DIM; k0 += 64) {
#pragma unroll
    for (int j = 0; j < 4; j++) {
      gld_lds16(aptr[j], lap[j]);
      gld_lds16(bptr[j], lbp[j]);
      aptr[j] += 64;
      bptr[j] += 64;
    }
    __syncthreads();
#pragma unroll
    for (int kk = 0; kk < 64; kk += 32) {
      bf16x8 af[4], bfr[4];
#pragma unroll
      for (int mi = 0; mi < 4; mi++)
        af[mi] = *(const bf16x8*)&lda[(wm + mi * 16 + (lane & 15)) * 64 + kk + ((lane >> 4) << 3)];
#pragma unroll
      for (int ni = 0; ni < 4; ni++)
        bfr[ni] = *(const bf16x8*)&ldb[(wn + ni * 16 + (lane & 15)) * 64 + kk + ((lane >> 4) << 3)];
#pragma unroll
      for (int mi = 0; mi < 4; mi++)
#pragma unroll
        for (int ni = 0; ni < 4; ni++)
          acc[mi][ni] = __builtin_amdgcn_mfma_f32_16x16x32_bf16(af[mi], bfr[ni], acc[mi][ni], 0, 0, 0);
    }
    __syncthreads();
  }

  // epilogue: C/D layout col=lane&15, row=(lane>>4)*4+reg  [m89-verified]
  const int quad = lane >> 4;
  const int cl = lane & 15;
#pragma unroll
  for (int ni = 0; ni < 4; ni++) {
    int col = nt * 128 + wn + ni * 16 + cl;
    float bval = bias[e * DIM + col];
#pragma unroll
    for (int mi = 0; mi < 4; mi++) {
#pragma unroll
      for (int reg = 0; reg < 4; reg++) {
        int rl = wm + mi * 16 + quad * 4 + reg;
        int r = mt * 128 + rl;
        if (r < n_e) {
          int pid = toks[rl];
          float v = acc[mi][ni][reg] + bval;
          if (MODE == 0) v = fmaxf(v, 0.f);
          else v *= pairw[pid];
          Out[(size_t)pid * DIM + col] = f2bf(v);
        }
      }
    }
  }
}

// ---------------- combine: y[t] = o_pair[2t] + o_pair[2t+1] (weights pre-folded) --------
__global__ __launch_bounds__(256) void combine_kernel(
    const unsigned short* __restrict__ o, float* __restrict__ y)
{
  const int t = blockIdx.x;
  const int tid = threadIdx.x;
  ushort4 a = ((const ushort4*)(o + (size_t)t * 2 * DIM))[tid];
  ushort4 b = ((const ushort4*)(o + (size_t)t * 2 * DIM + DIM))[tid];
  float4 r;
  r.x = bf2f(a.x) + bf2f(b.x);
  r.y = bf2f(a.y) + bf2f(b.y);
  r.z = bf2f(a.z) + bf2f(b.z);
  r.w = bf2f(a.w) + bf2f(b.w);
  ((float4*)(y + (size_t)t * DIM))[tid] = r;
}

extern "C" void kernel_launch(void* const* d_in, const int* in_sizes, int n_in,
                              void* d_out, int out_size, void* d_ws, size_t ws_size,
                              hipStream_t stream) {
  const float* x  = (const float*)d_in[0];
  const float* gW = (const float*)d_in[1];
  const float* gb = (const float*)d_in[2];
  const float* w1 = (const float*)d_in[3];
  const float* b1 = (const float*)d_in[4];
  const float* w2 = (const float*)d_in[5];
  const float* b2 = (const float*)d_in[6];
  float* y  = (float*)d_out;
  float* gp = (float*)d_out + (size_t)NTOK * DIM;

  // ws layout (bytes):
  //  [0,8M)    x_bf (bf16)          -- dead after gemm1; o_pair aliases [0,16M)
  //  [8M,24M)  w1_bf                -- dead after gemm1
  //  [24M,40M) w2_bf
  //  [40M,56M) h (bf16, row=pid)
  //  [56M,...) cnt(32B) | bucket(128KB) | pairw(32KB)
  char* ws = (char*)d_ws;
  unsigned short* x_bf   = (unsigned short*)(ws);
  unsigned short* w1_bf  = (unsigned short*)(ws + (size_t)(8u  << 20));
  unsigned short* w2_bf  = (unsigned short*)(ws + (size_t)(24u << 20));
  unsigned short* hbuf   = (unsigned short*)(ws + (size_t)(40u << 20));
  unsigned short* o_pair = (unsigned short*)(ws);   // alias, safe by kernel ordering
  int*   cnt    = (int*)(ws + (size_t)(56u << 20));
  int*   bucket = (int*)(ws + (size_t)(56u << 20) + 1024);
  float* pairw  = (float*)(ws + (size_t)(56u << 20) + 1024 + NE * NTOK * 4);

  hipMemsetAsync(cnt, 0, NE * sizeof(int), stream);
  gate_kernel<<<NTOK, 256, 0, stream>>>(x, gW, gb, x_bf, gp, cnt, bucket, pairw);
  const int cvt_blocks = (NE * DIM * DIM / 4) / 256;  // 8192
  cvt_kernel<<<cvt_blocks, 256, 0, stream>>>((const float4*)w1, (ushort4*)w1_bf);
  cvt_kernel<<<cvt_blocks, 256, 0, stream>>>((const float4*)w2, (ushort4*)w2_bf);
  dim3 gg(8, 32, NE);  // (n-tiles 1024/128, max m-tiles 4096/128, experts)
  ffn_gemm<0><<<gg, 256, 0, stream>>>(x_bf,  w1_bf, b1, cnt, bucket, pairw, hbuf);
  ffn_gemm<1><<<gg, 256, 0, stream>>>(hbuf, w2_bf, b2, cnt, bucket, pairw, o_pair);
  combine_kernel<<<NTOK, 256, 0, stream>>>(o_pair, y);
}

// Round 2
// 288.767 us; speedup vs baseline: 1.2550x; 1.2550x over previous
//
#include <hip/hip_runtime.h>

#define NTOK 4096
#define DIM 1024
#define NE 8

typedef __bf16 bf16x8 __attribute__((ext_vector_type(8)));
typedef float floatx4 __attribute__((ext_vector_type(4)));

__device__ __forceinline__ unsigned short f2bf(float f) {
  unsigned u = __float_as_uint(f);
  u = u + 0x7fffu + ((u >> 16) & 1u);
  return (unsigned short)(u >> 16);
}
__device__ __forceinline__ float bf2f(unsigned short h) {
  return __uint_as_float(((unsigned)h) << 16);
}

__device__ __forceinline__ void gld_lds16(const unsigned short* g, unsigned short* l) {
  __builtin_amdgcn_global_load_lds(
      (const __attribute__((address_space(1))) void*)g,
      (__attribute__((address_space(3))) void*)l, 16, 0, 0);
}

// ---------------- gating: one WAVE per token. logits, softmax, top-2, x->bf16 ----------
// No atomics here; binning is a separate wave-aggregated kernel.
__global__ __launch_bounds__(256) void gate_kernel(
    const float* __restrict__ x, const float* __restrict__ gW,
    const float* __restrict__ gb, unsigned short* __restrict__ x_bf,
    float* __restrict__ gp_out, int2* __restrict__ tops,
    float* __restrict__ pairw)
{
  const int tid = threadIdx.x;
  const int lane = tid & 63;
  const int wid = tid >> 6;
  const int t = blockIdx.x * 4 + wid;

  // load this token's row: 16 floats/lane, lane-contiguous float4s
  float4 xv[4];
#pragma unroll
  for (int j = 0; j < 4; j++)
    xv[j] = ((const float4*)(x + (size_t)t * DIM))[lane + 64 * j];
#pragma unroll
  for (int j = 0; j < 4; j++) {
    ushort4 xb;
    xb.x = f2bf(xv[j].x); xb.y = f2bf(xv[j].y);
    xb.z = f2bf(xv[j].z); xb.w = f2bf(xv[j].w);
    ((ushort4*)(x_bf + (size_t)t * DIM))[lane + 64 * j] = xb;
  }

  float p[NE];
#pragma unroll
  for (int e = 0; e < NE; e++) {
    const float4* gwe = (const float4*)(gW + e * DIM);
    float s = 0.f;
#pragma unroll
    for (int j = 0; j < 4; j++) {
      float4 g = gwe[lane + 64 * j];
      s += xv[j].x * g.x + xv[j].y * g.y + xv[j].z * g.z + xv[j].w * g.w;
    }
    p[e] = s;
  }
  // full-wave xor reduction: every lane ends with the complete dot product
#pragma unroll
  for (int e = 0; e < NE; e++) {
#pragma unroll
    for (int off = 32; off >= 1; off >>= 1) p[e] += __shfl_xor(p[e], off);
  }

  // softmax (redundant across lanes, registers only)
  float m = -1e30f;
#pragma unroll
  for (int e = 0; e < NE; e++) { p[e] += gb[e]; m = fmaxf(m, p[e]); }
  float s = 0.f;
  float pr[NE];
#pragma unroll
  for (int e = 0; e < NE; e++) { pr[e] = __expf(p[e] - m); s += pr[e]; }
  float inv = 1.f / s;
#pragma unroll
  for (int e = 0; e < NE; e++) pr[e] *= inv;

  if (lane < NE) gp_out[(size_t)t * NE + lane] = pr[lane];

  if (lane == 0) {
    // top-2 (ties -> lowest index, matching lax.top_k)
    int i0 = 0;
#pragma unroll
    for (int e = 1; e < NE; e++) if (pr[e] > pr[i0]) i0 = e;
    int i1 = (i0 == 0) ? 1 : 0;
#pragma unroll
    for (int e = 0; e < NE; e++) if (e != i0 && pr[e] > pr[i1]) i1 = e;
    // renormalize: softmax over the two top probabilities (per reference)
    float d = __expf(pr[i1] - pr[i0]);
    float w0 = 1.f / (1.f + d);
    tops[t] = make_int2(i0, i1);
    pairw[t * 2] = w0;
    pairw[t * 2 + 1] = 1.f - w0;
  }
}

// ---------------- binning: wave-aggregated atomics (1 atomic / expert / wave) ----------
__global__ __launch_bounds__(256) void bin_kernel(
    const int2* __restrict__ tops, int* __restrict__ cnt,
    int* __restrict__ bucket)
{
  const int t = blockIdx.x * 256 + threadIdx.x;
  const int lane = threadIdx.x & 63;
  int2 ti = tops[t];
#pragma unroll
  for (int slot = 0; slot < 2; slot++) {
    int e = slot ? ti.y : ti.x;
#pragma unroll
    for (int ex = 0; ex < NE; ex++) {
      bool mine = (e == ex);
      unsigned long long mask = __ballot(mine);
      if (mask) {  // wave-uniform
        int leader = __ffsll((long long)mask) - 1;
        int total = __popcll(mask);
        int prefix = __popcll(mask & ((1ull << lane) - 1ull));
        int base = 0;
        if (lane == leader) base = atomicAdd(&cnt[ex], total);
        base = __shfl(base, leader);
        if (mine) bucket[ex * NTOK + base + prefix] = t * 2 + slot;
      }
    }
  }
}

// ---------------- fp32 -> bf16 weight conversion ----------------
__global__ __launch_bounds__(256) void cvt_kernel(
    const float4* __restrict__ src, ushort4* __restrict__ dst)
{
  int i = blockIdx.x * 256 + threadIdx.x;
  float4 v = src[i];
  ushort4 o;
  o.x = f2bf(v.x); o.y = f2bf(v.y); o.z = f2bf(v.z); o.w = f2bf(v.w);
  dst[i] = o;
}

// ---------------- grouped expert GEMM (128x128 tile, BK=64, 16x16x32 bf16 MFMA) ----------
// MODE 0: A = x_bf gathered by token (pid>>1), out = relu(acc + b1) -> h[pid]
// MODE 1: A = h gathered by pid,            out = (acc + b2) * pairw[pid] -> o_pair[pid]
template <int MODE>
__global__ __launch_bounds__(256) void ffn_gemm(
    const unsigned short* __restrict__ A,
    const unsigned short* __restrict__ B,     // [E][DIM][DIM] bf16, row-major (out,in)
    const float* __restrict__ bias,           // [E][DIM]
    const int* __restrict__ cnt, const int* __restrict__ bucket,
    const float* __restrict__ pairw,
    unsigned short* __restrict__ Out)
{
  const int nt = blockIdx.x;
  const int mt = blockIdx.y;
  const int e  = blockIdx.z;
  const int n_e = cnt[e];
  if (mt * 128 >= n_e) return;

  __shared__ unsigned short lda[128 * 64];
  __shared__ unsigned short ldb[128 * 64];
  __shared__ int toks[128];

  const int tid = threadIdx.x;
  const int lane = tid & 63;
  const int wid = tid >> 6;

  if (tid < 128) {
    int r = mt * 128 + tid;
    if (r >= n_e) r = n_e - 1;     // clamp: duplicate row, store-masked later
    toks[tid] = bucket[e * NTOK + r];
  }
  __syncthreads();

  // staging addresses: group g = wid*4+j covers tile rows g*8..g*8+7 (1 KiB per inst)
  const unsigned short* aptr[4];
  const unsigned short* bptr[4];
  unsigned short* lap[4];
  unsigned short* lbp[4];
#pragma unroll
  for (int j = 0; j < 4; j++) {
    int g = wid * 4 + j;
    int row = g * 8 + (lane >> 3);
    int pid = toks[row];
    int arow = (MODE == 0) ? (pid >> 1) : pid;
    aptr[j] = A + (size_t)arow * DIM + ((lane & 7) << 3);
    lap[j] = lda + g * 512;
    int brow = nt * 128 + row;
    bptr[j] = B + (size_t)e * DIM * DIM + (size_t)brow * DIM + ((lane & 7) << 3);
    lbp[j] = ldb + g * 512;
  }

  floatx4 acc[4][4] = {};
  const int wm = (wid & 1) * 64;
  const int wn = (wid >> 1) * 64;

  for (int k0 = 0; k0 < DIM; k0 += 64) {
#pragma unroll
    for (int j = 0; j < 4; j++) {
      gld_lds16(aptr[j], lap[j]);
      gld_lds16(bptr[j], lbp[j]);
      aptr[j] += 64;
      bptr[j] += 64;
    }
    __syncthreads();
#pragma unroll
    for (int kk = 0; kk < 64; kk += 32) {
      bf16x8 af[4], bfr[4];
#pragma unroll
      for (int mi = 0; mi < 4; mi++)
        af[mi] = *(const bf16x8*)&lda[(wm + mi * 16 + (lane & 15)) * 64 + kk + ((lane >> 4) << 3)];
#pragma unroll
      for (int ni = 0; ni < 4; ni++)
        bfr[ni] = *(const bf16x8*)&ldb[(wn + ni * 16 + (lane & 15)) * 64 + kk + ((lane >> 4) << 3)];
#pragma unroll
      for (int mi = 0; mi < 4; mi++)
#pragma unroll
        for (int ni = 0; ni < 4; ni++)
          acc[mi][ni] = __builtin_amdgcn_mfma_f32_16x16x32_bf16(af[mi], bfr[ni], acc[mi][ni], 0, 0, 0);
    }
    __syncthreads();
  }

  // epilogue: C/D layout col=lane&15, row=(lane>>4)*4+reg  [m89-verified]
  const int quad = lane >> 4;
  const int cl = lane & 15;
#pragma unroll
  for (int ni = 0; ni < 4; ni++) {
    int col = nt * 128 + wn + ni * 16 + cl;
    float bval = bias[e * DIM + col];
#pragma unroll
    for (int mi = 0; mi < 4; mi++) {
#pragma unroll
      for (int reg = 0; reg < 4; reg++) {
        int rl = wm + mi * 16 + quad * 4 + reg;
        int r = mt * 128 + rl;
        if (r < n_e) {
          int pid = toks[rl];
          float v = acc[mi][ni][reg] + bval;
          if (MODE == 0) v = fmaxf(v, 0.f);
          else v *= pairw[pid];
          Out[(size_t)pid * DIM + col] = f2bf(v);
        }
      }
    }
  }
}

// ---------------- combine: y[t] = o_pair[2t] + o_pair[2t+1] (weights pre-folded) --------
__global__ __launch_bounds__(256) void combine_kernel(
    const unsigned short* __restrict__ o, float* __restrict__ y)
{
  const int t = blockIdx.x;
  const int tid = threadIdx.x;
  ushort4 a = ((const ushort4*)(o + (size_t)t * 2 * DIM))[tid];
  ushort4 b = ((const ushort4*)(o + (size_t)t * 2 * DIM + DIM))[tid];
  float4 r;
  r.x = bf2f(a.x) + bf2f(b.x);
  r.y = bf2f(a.y) + bf2f(b.y);
  r.z = bf2f(a.z) + bf2f(b.z);
  r.w = bf2f(a.w) + bf2f(b.w);
  ((float4*)(y + (size_t)t * DIM))[tid] = r;
}

extern "C" void kernel_launch(void* const* d_in, const int* in_sizes, int n_in,
                              void* d_out, int out_size, void* d_ws, size_t ws_size,
                              hipStream_t stream) {
  const float* x  = (const float*)d_in[0];
  const float* gW = (const float*)d_in[1];
  const float* gb = (const float*)d_in[2];
  const float* w1 = (const float*)d_in[3];
  const float* b1 = (const float*)d_in[4];
  const float* w2 = (const float*)d_in[5];
  const float* b2 = (const float*)d_in[6];
  float* y  = (float*)d_out;
  float* gp = (float*)d_out + (size_t)NTOK * DIM;

  // ws layout (bytes):
  //  [0,8M)    x_bf (bf16)          -- dead after gemm1; o_pair aliases [0,16M)
  //  [8M,24M)  w1_bf                -- dead after gemm1
  //  [24M,40M) w2_bf
  //  [40M,56M) h (bf16, row=pid)
  //  [56M,...) cnt(32B) | bucket(128KB) | pairw(32KB) | tops(32KB)
  char* ws = (char*)d_ws;
  unsigned short* x_bf   = (unsigned short*)(ws);
  unsigned short* w1_bf  = (unsigned short*)(ws + (size_t)(8u  << 20));
  unsigned short* w2_bf  = (unsigned short*)(ws + (size_t)(24u << 20));
  unsigned short* hbuf   = (unsigned short*)(ws + (size_t)(40u << 20));
  unsigned short* o_pair = (unsigned short*)(ws);   // alias, safe by kernel ordering
  char* tail = ws + (size_t)(56u << 20);
  int*   cnt    = (int*)(tail);
  int*   bucket = (int*)(tail + 1024);
  float* pairw  = (float*)(tail + 1024 + NE * NTOK * 4);
  int2*  tops   = (int2*) (tail + 1024 + NE * NTOK * 4 + NTOK * 2 * 4);

  hipMemsetAsync(cnt, 0, NE * sizeof(int), stream);
  gate_kernel<<<NTOK / 4, 256, 0, stream>>>(x, gW, gb, x_bf, gp, tops, pairw);
  bin_kernel<<<NTOK / 256, 256, 0, stream>>>(tops, cnt, bucket);
  const int cvt_blocks = (NE * DIM * DIM / 4) / 256;  // 8192
  cvt_kernel<<<cvt_blocks, 256, 0, stream>>>((const float4*)w1, (ushort4*)w1_bf);
  cvt_kernel<<<cvt_blocks, 256, 0, stream>>>((const float4*)w2, (ushort4*)w2_bf);
  dim3 gg(8, 32, NE);  // (n-tiles 1024/128, max m-tiles 4096/128, experts)
  ffn_gemm<0><<<gg, 256, 0, stream>>>(x_bf,  w1_bf, b1, cnt, bucket, pairw, hbuf);
  ffn_gemm<1><<<gg, 256, 0, stream>>>(hbuf, w2_bf, b2, cnt, bucket, pairw, o_pair);
  combine_kernel<<<NTOK, 256, 0, stream>>>(o_pair, y);
}